// Round 7
// baseline (1670.667 us; speedup 1.0000x reference)
//
#include <hip/hip_runtime.h>
#include <hip/hip_bf16.h>

#define DEVI __device__ __forceinline__

typedef short bf16x8 __attribute__((ext_vector_type(8)));
typedef float f32x4  __attribute__((ext_vector_type(4)));
typedef float f32x16 __attribute__((ext_vector_type(16)));
typedef unsigned short u16;
typedef unsigned int u32;

using bf16 = __hip_bfloat16;

DEVI bf16x8 ld8(const bf16* p) { return *reinterpret_cast<const bf16x8*>(p); }

DEVI u16 f2bu(float f) {
  union { bf16 h; u16 u; } c; c.h = __float2bfloat16(f); return c.u;
}
DEVI float b2f(u16 u) {
  union { float f; unsigned int i; } c; c.i = ((unsigned int)u) << 16; return c.f;
}

DEVI void gload_lds16(const bf16* g, bf16* l) {
  typedef const __attribute__((address_space(1))) char* gp_t;
  typedef __attribute__((address_space(3))) char* lp_t;
  __builtin_amdgcn_global_load_lds((gp_t)(const void*)g, (lp_t)(void*)l, 16, 0, 0);
}

#define MFMA16(a, b, c) __builtin_amdgcn_mfma_f32_16x16x32_bf16((a), (b), (c), 0, 0, 0)
#define MFMA32(a, b, c) __builtin_amdgcn_mfma_f32_32x32x16_bf16((a), (b), (c), 0, 0, 0)

// Sizes: B=4, C=256, N=4096 (64x64), 3C=768, groups=32 (8 ch each)

// ---------------- K0: weights fp32 -> bf16 ----------------
__global__ __launch_bounds__(256) void wconv_kernel(const float* __restrict__ wq,
                                                    const float* __restrict__ wp,
                                                    bf16* __restrict__ wqb,
                                                    bf16* __restrict__ wpb) {
  int tid = blockIdx.x * 256 + threadIdx.x;
  const bool isq = tid < 49152;
  float4 v = isq ? ((const float4*)wq)[tid] : ((const float4*)wp)[tid - 49152];
  alignas(8) bf16 o[4] = { __float2bfloat16(v.x), __float2bfloat16(v.y),
                           __float2bfloat16(v.z), __float2bfloat16(v.w) };
  uint2 pk = *reinterpret_cast<uint2*>(o);
  if (isq) ((uint2*)wqb)[tid] = pk;
  else     ((uint2*)wpb)[tid - 49152] = pk;
}

// ---------------- K1: GroupNorm -> ht[b][n][c] bf16 ----------------
__global__ __launch_bounds__(256) void gn_kernel(const float* __restrict__ x,
                                                 const float* __restrict__ gw,
                                                 const float* __restrict__ gb,
                                                 bf16* __restrict__ ht) {
  const int blk = blockIdx.x;            // b*32 + g
  const int bb = blk >> 5, g = blk & 31;
  const float* xg = x + (size_t)(bb * 256 + g * 8) * 4096;

  float s = 0.f, ss = 0.f;
  const float4* x4 = (const float4*)xg;
  for (int i = threadIdx.x; i < 8192; i += 256) {
    float4 v = x4[i];
    s  += v.x + v.y + v.z + v.w;
    ss += v.x * v.x + v.y * v.y + v.z * v.z + v.w * v.w;
  }
  #pragma unroll
  for (int off = 32; off; off >>= 1) {
    s  += __shfl_down(s, off);
    ss += __shfl_down(ss, off);
  }
  __shared__ float red[8];
  int wave = threadIdx.x >> 6;
  if ((threadIdx.x & 63) == 0) { red[wave * 2] = s; red[wave * 2 + 1] = ss; }
  __syncthreads();
  if (threadIdx.x == 0) {
    float S = red[0] + red[2] + red[4] + red[6];
    float SS = red[1] + red[3] + red[5] + red[7];
    float mu = S * (1.f / 32768.f);
    float var = SS * (1.f / 32768.f) - mu * mu;
    red[0] = mu; red[1] = rsqrtf(var + 1e-5f);
  }
  __syncthreads();
  const float mu = red[0], rstd = red[1];

  float gm[8], bt[8];
  #pragma unroll
  for (int j = 0; j < 8; ++j) {
    float wv = gw[g * 8 + j] * rstd;
    gm[j] = wv; bt[j] = gb[g * 8 + j] - mu * wv;
  }
  bf16* hrow = ht + (size_t)bb * 4096 * 256 + g * 8;
  for (int n = threadIdx.x; n < 4096; n += 256) {
    alignas(16) u16 u[8];
    #pragma unroll
    for (int j = 0; j < 8; ++j)
      u[j] = f2bu(xg[j * 4096 + n] * gm[j] + bt[j]);
    *reinterpret_cast<uint4*>(hrow + (size_t)n * 256) = *reinterpret_cast<uint4*>(u);
  }
}

// ---------------- K2: QKV GEMM (staged), qkvt[n][o] = ht[n][c]*W[o][c]^T + bias ----------------
__global__ __launch_bounds__(256, 2) void qkv_gemm(const bf16* __restrict__ ht,
                                                   const bf16* __restrict__ wq,
                                                   const float* __restrict__ qkvb,
                                                   bf16* __restrict__ qkvt) {
  const int phys = blockIdx.x;
  const int L = (phys & 7) * 96 + (phys >> 3);
  const int bb = L / 192; const int rem = L - bb * 192;
  const int nt = rem / 6, ot = rem - nt * 6;

  const int tid = threadIdx.x, lane = tid & 63, w = tid >> 6;
  const int ln = lane & 15, hi = lane >> 4;
  const int wr = w >> 1, wc = w & 1;
  const int n_base = nt * 128, o_base = ot * 128;
  const bf16* hb = ht + (size_t)bb * 4096 * 256;

  __shared__ bf16 At[2][128 * 64];   // row-major [128][64ch], slot swz: g ^= (row&7)
  __shared__ bf16 Bt[2][128 * 64];

  f32x4 acc[4][4] = {};

  {
    #pragma unroll
    for (int i = 0; i < 4; ++i) {
      int G = i * 256 + tid; int row = G >> 3, g = G & 7;
      int cofs = (g ^ (row & 7)) << 3;
      gload_lds16(hb + (size_t)(n_base + row) * 256 + cofs, At[0] + (size_t)G * 8);
      gload_lds16(wq + (size_t)(o_base + row) * 256 + cofs, Bt[0] + (size_t)G * 8);
    }
  }
  __syncthreads();

  int cur = 0;
  for (int ks = 0; ks < 4; ++ks) {
    if (ks < 3) {
      int k0 = (ks + 1) * 64;
      #pragma unroll
      for (int i = 0; i < 4; ++i) {
        int G = i * 256 + tid; int row = G >> 3, g = G & 7;
        int cofs = k0 + ((g ^ (row & 7)) << 3);
        gload_lds16(hb + (size_t)(n_base + row) * 256 + cofs, At[cur ^ 1] + (size_t)G * 8);
        gload_lds16(wq + (size_t)(o_base + row) * 256 + cofs, Bt[cur ^ 1] + (size_t)G * 8);
      }
    }
    const char* Ab = (const char*)At[cur];
    const char* Bb = (const char*)Bt[cur];
    __builtin_amdgcn_s_setprio(1);
    #pragma unroll
    for (int cb = 0; cb < 2; ++cb) {
      bf16x8 af[4], bfr[4];
      #pragma unroll
      for (int i = 0; i < 4; ++i) {
        int row = wr * 64 + i * 16 + ln;
        af[i] = *(const bf16x8*)(Ab + row * 128 + (((cb * 4 + hi) ^ (row & 7)) << 4));
      }
      #pragma unroll
      for (int j = 0; j < 4; ++j) {
        int row = wc * 64 + j * 16 + ln;
        bfr[j] = *(const bf16x8*)(Bb + row * 128 + (((cb * 4 + hi) ^ (row & 7)) << 4));
      }
      #pragma unroll
      for (int i = 0; i < 4; ++i)
        #pragma unroll
        for (int j = 0; j < 4; ++j)
          acc[i][j] = MFMA16(af[i], bfr[j], acc[i][j]);
    }
    __builtin_amdgcn_s_setprio(0);
    __syncthreads();
    cur ^= 1;
  }

  const float sc = (ot < 2) ? 0.0625f : 1.0f;   // fold 1/sqrt(C)=1/16 into Q
  bf16* ob = qkvt + (size_t)bb * 4096 * 768;
  #pragma unroll
  for (int j = 0; j < 4; ++j) {
    int o = o_base + wc * 64 + j * 16 + ln;
    float bias = qkvb[o];
    #pragma unroll
    for (int i = 0; i < 4; ++i)
      #pragma unroll
      for (int r = 0; r < 4; ++r) {
        int n = n_base + wr * 64 + i * 16 + hi * 4 + r;
        ob[(size_t)n * 768 + o] = __float2bfloat16((acc[i][j][r] + bias) * sc);
      }
  }
}

// ---------------- K3a: K -> fragment-major K_frag ----------------
// K_frag[bb][kvb][(s2h*32 + r)*8 + j] = K[kvb*32+r][s2h*8+j]; 16KB per kvb tile.
__global__ __launch_bounds__(256) void kprep_kernel(const bf16* __restrict__ qkvt,
                                                    bf16* __restrict__ Kf) {
  int bb = blockIdx.x >> 7, kvb = blockIdx.x & 127;
  const bf16* src = qkvt + (size_t)bb * 4096 * 768 + (size_t)kvb * 32 * 768 + 256;
  bf16* dst = Kf + (size_t)bb * 1048576 + (size_t)kvb * 8192;
  #pragma unroll
  for (int i = 0; i < 4; ++i) {
    int cid = i * 256 + threadIdx.x;          // 0..1023 = s2h*32 + r
    int r = cid & 31, s2h = cid >> 5;
    bf16x8 v = ld8(src + (size_t)r * 768 + s2h * 8);
    *reinterpret_cast<bf16x8*>(dst + (size_t)cid * 8) = v;
  }
}

// ---------------- K3b: V -> fragment-major V_frag (via LDS transpose) ----------------
// V_frag[bb][kvb][(p2h*256 + c)*8 + j] = V[kvb*32 + p2h*8 + j][c]; 16KB per kvb.
__global__ __launch_bounds__(256) void vfrag_kernel(const bf16* __restrict__ qkvt,
                                                    bf16* __restrict__ Vf) {
  int bid = blockIdx.x;
  int ct = bid & 3, ntile = (bid >> 2) & 63, bb = bid >> 8;
  __shared__ bf16 T[64][72];
  int tid = threadIdx.x;
  int i = tid >> 3, j8 = (tid & 7) * 8;
  const bf16* src = qkvt + (size_t)bb * 4096 * 768 + (size_t)(ntile * 64 + i) * 768 + 512 + ct * 64 + j8;
  #pragma unroll
  for (int p = 0; p < 2; ++p) {
    bf16x8 v = ld8(src + (size_t)p * 32 * 768);
    *reinterpret_cast<bf16x8*>(&T[i + p * 32][j8]) = v;   // T[n-local][c-local]
  }
  __syncthreads();
  #pragma unroll
  for (int p = 0; p < 2; ++p) {
    int u = p * 256 + tid;                    // 0..511
    int c_local = u & 63, p2h = (u >> 6) & 3, kvb2 = u >> 8;
    int kvb = ntile * 2 + kvb2;
    int c = ct * 64 + c_local;
    alignas(16) u16 tmp[8];
    #pragma unroll
    for (int j = 0; j < 8; ++j) {
      union { bf16 h; u16 b; } cv; cv.h = T[kvb2 * 32 + p2h * 8 + j][c_local];
      tmp[j] = cv.b;
    }
    *reinterpret_cast<uint4*>(Vf + (size_t)bb * 1048576 + (size_t)kvb * 8192 +
                              ((size_t)p2h * 256 + c) * 8) = *reinterpret_cast<uint4*>(tmp);
  }
}

// ---------------- K4: flash attention, barrier-free frag-major loads ----------------
// grid 1024, 256 thr (4 waves). Wave pair (qhalf) shares 32 q-rows; kvhalf splits the
// kv slice in half; end-of-kernel pair merge via LDS. 4 blocks/CU = 16 waves/CU.
__global__ __launch_bounds__(256, 4) void attn_kernel(const bf16* __restrict__ qkvt,
                                                      const bf16* __restrict__ Kf,
                                                      const bf16* __restrict__ Vf,
                                                      bf16* __restrict__ Opart,
                                                      float* __restrict__ ml) {
  const int phys = blockIdx.x;
  const int xcd = phys & 7, local = phys >> 3;       // 2 (bb,sp) slices per XCD
  const int gs = xcd * 2 + (local >> 6);             // 0..15 = bb*4+sp
  const int qt = local & 63;
  const int bb = gs >> 2, sp = gs & 3;

  const int tid = threadIdx.x, lane = tid & 63, w = tid >> 6;
  const int ln32 = lane & 31, h = lane >> 5;
  const bool h0 = (h == 0);
  const int qhalf = w >> 1, kvhalf = w & 1;
  const int n0w = qt * 64 + qhalf * 32;

  const bf16* qb = qkvt + (size_t)bb * 4096 * 768;
  const bf16* kb = Kf + (size_t)bb * 1048576;
  const bf16* vb = Vf + (size_t)bb * 1048576;

  // Q fragments (B-operand of S^T mfma): 32 q-rows x 256 ch (pre-scaled 1/16)
  bf16x8 aq[16];
  #pragma unroll
  for (int step = 0; step < 16; ++step)
    aq[step] = ld8(qb + (size_t)(n0w + ln32) * 768 + step * 16 + h * 8);

  f32x16 acc[8] = {};
  float m_run = -3.0e38f, lsum = 0.f;

  for (int t = 0; t < 16; ++t) {
    const int kvb = sp * 32 + kvhalf * 16 + t;
    const bf16* kt = kb + (size_t)kvb * 8192;
    const bf16* vt = vb + (size_t)kvb * 8192;

    // ---- S^T = K . Q^T : lane holds P-row q=ln32, kv = (r&3)+8*(r>>2)+4h ----
    f32x16 s0 = {};
    __builtin_amdgcn_s_setprio(1);
    #pragma unroll
    for (int step = 0; step < 16; ++step) {
      bf16x8 k0 = ld8(kt + ((step * 2 + h) * 32 + ln32) * 8);
      s0 = MFMA32(k0, aq[step], s0);
    }
    __builtin_amdgcn_s_setprio(0);

    // ---- row max ----
    float mx = -3.0e38f;
    #pragma unroll
    for (int r = 0; r < 16; ++r) mx = fmaxf(mx, s0[r]);
    mx = fmaxf(mx, __shfl_xor(mx, 32));

    // ---- defer-max rescale ----
    if (__any(mx > m_run + 8.f)) {
      float mnew = fmaxf(m_run, mx);
      float alpha = __expf(m_run - mnew);
      m_run = mnew;
      lsum *= alpha;
      #pragma unroll
      for (int r = 0; r < 16; ++r) {
        int qacc = (r & 3) + 8 * (r >> 2) + 4 * h;
        float ar = __shfl(alpha, qacc);
        #pragma unroll
        for (int ct = 0; ct < 8; ++ct) acc[ct][r] *= ar;
      }
    }

    // ---- P = exp(S - m); packs; cross-half swap ----
    u32 pk0[8], sw0[8];
    #pragma unroll
    for (int m = 0; m < 8; ++m) {
      float a0 = __expf(s0[2 * m] - m_run), b0 = __expf(s0[2 * m + 1] - m_run);
      lsum += a0 + b0;
      pk0[m] = ((u32)f2bu(b0) << 16) | f2bu(a0);
    }
    #pragma unroll
    for (int m = 0; m < 8; ++m) sw0[m] = __shfl_xor(pk0[m], 32);

    // ---- O += P V ----
    __builtin_amdgcn_s_setprio(1);
    #pragma unroll
    for (int st = 0; st < 2; ++st) {
      const int A0 = 4 * st, A1 = A0 + 2;
      union { bf16x8 v; u32 u[4]; } af;
      af.u[0] = h0 ? pk0[A0]     : sw0[A1];
      af.u[1] = h0 ? pk0[A0 + 1] : sw0[A1 + 1];
      af.u[2] = h0 ? sw0[A0]     : pk0[A1];
      af.u[3] = h0 ? sw0[A0 + 1] : pk0[A1 + 1];
      #pragma unroll
      for (int ct = 0; ct < 8; ++ct) {
        bf16x8 bv = ld8(vt + ((st * 2 + h) * 256 + ct * 32 + ln32) * 8);
        acc[ct] = MFMA32(af.v, bv, acc[ct]);
      }
    }
    __builtin_amdgcn_s_setprio(0);
  }

  float Lrow = lsum + __shfl_xor(lsum, 32);

  // ---- pair merge (kvhalf 1 -> LDS; kvhalf 0 merges + writes) ----
  __shared__ bf16 Mg[2][32][256];
  __shared__ float MLg[2][32][2];
  if (kvhalf == 1) {
    #pragma unroll
    for (int r = 0; r < 16; ++r) {
      int qacc = (r & 3) + 8 * (r >> 2) + 4 * h;
      #pragma unroll
      for (int ct = 0; ct < 8; ++ct)
        Mg[qhalf][qacc][ct * 32 + ln32] = __float2bfloat16(acc[ct][r]);
    }
    if (lane < 32) { MLg[qhalf][lane][0] = m_run; MLg[qhalf][lane][1] = Lrow; }
  }
  __syncthreads();
  if (kvhalf == 0) {
    size_t rb = (size_t)sp * 16384 + (size_t)bb * 4096;
    if (lane < 32) {
      float m2 = MLg[qhalf][lane][0], l2 = MLg[qhalf][lane][1];
      float M = fmaxf(m_run, m2);
      float L = Lrow * __expf(m_run - M) + l2 * __expf(m2 - M);
      ml[(rb + n0w + lane) * 2]     = M;
      ml[(rb + n0w + lane) * 2 + 1] = L;
    }
    bf16* ob = Opart + rb * 256;
    #pragma unroll
    for (int r = 0; r < 16; ++r) {
      int qacc = (r & 3) + 8 * (r >> 2) + 4 * h;
      float m1r = __shfl(m_run, qacc);
      float l1r_unused = 0.f; (void)l1r_unused;
      float m2r = MLg[qhalf][qacc][0];
      float Mr = fmaxf(m1r, m2r);
      float a1 = __expf(m1r - Mr), a2 = __expf(m2r - Mr);
      int n = n0w + qacc;
      #pragma unroll
      for (int ct = 0; ct < 8; ++ct) {
        union { bf16 hh; u16 b; } cv; cv.hh = Mg[qhalf][qacc][ct * 32 + ln32];
        ob[(size_t)n * 256 + ct * 32 + ln32] =
            __float2bfloat16(acc[ct][r] * a1 + b2f(cv.b) * a2);
      }
    }
  }
}

// ---------------- K4b: combine split-KV partials -> ho[b][n][c] ----------------
__global__ __launch_bounds__(256) void combine_kernel(const bf16* __restrict__ Opart,
                                                      const float* __restrict__ ml,
                                                      bf16* __restrict__ ho) {
  int rowg = blockIdx.x * 32 + (threadIdx.x >> 3);   // b*4096 + n
  int cg = (threadIdx.x & 7) * 32;
  float msp[4]; float M = -3.0e38f;
  #pragma unroll
  for (int sp = 0; sp < 4; ++sp) {
    msp[sp] = ml[((size_t)sp * 16384 + rowg) * 2];
    M = fmaxf(M, msp[sp]);
  }
  float acc[32];
  #pragma unroll
  for (int j = 0; j < 32; ++j) acc[j] = 0.f;
  float Ltot = 0.f;
  #pragma unroll
  for (int sp = 0; sp < 4; ++sp) {
    float sc = __expf(msp[sp] - M);
    Ltot += ml[((size_t)sp * 16384 + rowg) * 2 + 1] * sc;
    const bf16* p = Opart + ((size_t)sp * 16384 + rowg) * 256 + cg;
    #pragma unroll
    for (int v = 0; v < 4; ++v) {
      bf16x8 u = ld8(p + v * 8);
      #pragma unroll
      for (int j = 0; j < 8; ++j) acc[v * 8 + j] += sc * b2f((u16)u[j]);
    }
  }
  float inv = 1.f / Ltot;
  bf16* o = ho + (size_t)rowg * 256 + cg;
  #pragma unroll
  for (int v = 0; v < 4; ++v) {
    alignas(16) u16 u[8];
    #pragma unroll
    for (int j = 0; j < 8; ++j) u[j] = f2bu(acc[v * 8 + j] * inv);
    *reinterpret_cast<uint4*>(o + v * 8) = *reinterpret_cast<uint4*>(u);
  }
}

// ---------------- K5: proj GEMM (staged) + residual ----------------
__global__ __launch_bounds__(256, 2) void proj_gemm(const bf16* __restrict__ ho,
                                                    const bf16* __restrict__ wp,
                                                    const float* __restrict__ pb,
                                                    const float* __restrict__ x,
                                                    float* __restrict__ out) {
  const int phys = blockIdx.x;
  const int L = (phys & 7) * 32 + (phys >> 3);
  const int bb = L >> 6; const int rem = L & 63;
  const int ot = rem >> 5, nt = rem & 31;

  const int tid = threadIdx.x, lane = tid & 63, w = tid >> 6;
  const int ln = lane & 15, hi = lane >> 4;
  const int wr = w >> 1, wc = w & 1;
  const int o_base = ot * 128, n_base = nt * 128;
  const bf16* hb = ho + (size_t)bb * 4096 * 256;

  __shared__ bf16 Wt[2][128 * 64];
  __shared__ bf16 Ht[2][128 * 64];

  f32x4 acc[4][4] = {};

  {
    #pragma unroll
    for (int i = 0; i < 4; ++i) {
      int G = i * 256 + tid; int row = G >> 3, g = G & 7;
      int cofs = (g ^ (row & 7)) << 3;
      gload_lds16(wp + (size_t)(o_base + row) * 256 + cofs, Wt[0] + (size_t)G * 8);
      gload_lds16(hb + (size_t)(n_base + row) * 256 + cofs, Ht[0] + (size_t)G * 8);
    }
  }
  __syncthreads();

  int cur = 0;
  for (int ks = 0; ks < 4; ++ks) {
    if (ks < 3) {
      int k0 = (ks + 1) * 64;
      #pragma unroll
      for (int i = 0; i < 4; ++i) {
        int G = i * 256 + tid; int row = G >> 3, g = G & 7;
        int cofs = k0 + ((g ^ (row & 7)) << 3);
        gload_lds16(wp + (size_t)(o_base + row) * 256 + cofs, Wt[cur ^ 1] + (size_t)G * 8);
        gload_lds16(hb + (size_t)(n_base + row) * 256 + cofs, Ht[cur ^ 1] + (size_t)G * 8);
      }
    }
    const char* Ab = (const char*)Wt[cur];
    const char* Bb = (const char*)Ht[cur];
    __builtin_amdgcn_s_setprio(1);
    #pragma unroll
    for (int cb = 0; cb < 2; ++cb) {
      bf16x8 af[4], bfr[4];
      #pragma unroll
      for (int i = 0; i < 4; ++i) {
        int row = wr * 64 + i * 16 + ln;
        af[i] = *(const bf16x8*)(Ab + row * 128 + (((cb * 4 + hi) ^ (row & 7)) << 4));
      }
      #pragma unroll
      for (int j = 0; j < 4; ++j) {
        int row = wc * 64 + j * 16 + ln;
        bfr[j] = *(const bf16x8*)(Bb + row * 128 + (((cb * 4 + hi) ^ (row & 7)) << 4));
      }
      #pragma unroll
      for (int i = 0; i < 4; ++i)
        #pragma unroll
        for (int j = 0; j < 4; ++j)
          acc[i][j] = MFMA16(af[i], bfr[j], acc[i][j]);
    }
    __builtin_amdgcn_s_setprio(0);
    __syncthreads();
    cur ^= 1;
  }

  const float* xb = x + (size_t)bb * 256 * 4096;
  float* ob = out + (size_t)bb * 256 * 4096;
  #pragma unroll
  for (int i = 0; i < 4; ++i)
    #pragma unroll
    for (int r = 0; r < 4; ++r) {
      int o = o_base + wr * 64 + i * 16 + hi * 4 + r;
      float bias = pb[o];
      #pragma unroll
      for (int j = 0; j < 4; ++j) {
        int n = n_base + wc * 64 + j * 16 + ln;
        size_t idx = (size_t)o * 4096 + n;
        ob[idx] = xb[idx] + bias + acc[i][j][r];
      }
    }
}

extern "C" void kernel_launch(void* const* d_in, const int* in_sizes, int n_in,
                              void* d_out, int out_size, void* d_ws, size_t ws_size,
                              hipStream_t stream) {
  const float* x   = (const float*)d_in[0];
  const float* gnw = (const float*)d_in[1];
  const float* gnb = (const float*)d_in[2];
  const float* qw  = (const float*)d_in[3];
  const float* qb  = (const float*)d_in[4];
  const float* pw  = (const float*)d_in[5];
  const float* pb  = (const float*)d_in[6];
  float* out = (float*)d_out;

  char* ws = (char*)d_ws;
  bf16* ht    = (bf16*)(ws);                               // [4][4096][256]  0..8 MB (dead after qkv)
  bf16* Kf    = (bf16*)(ws);                               // K_frag reuses ht region
  bf16* qkvt  = (bf16*)(ws + ((size_t)8 << 20));           // [4][4096][768]  8..32 MB
  bf16* Vf    = (bf16*)(ws + ((size_t)32 << 20));          // V_frag [4][1M]  32..40 MB
  bf16* ho    = (bf16*)(ws + ((size_t)40 << 20));          // [4][4096][256]  40..48 MB
  bf16* wqb   = (bf16*)(ws + ((size_t)48 << 20));          // [768][256]
  bf16* wpb   = (bf16*)(ws + ((size_t)48 << 20) + 768 * 256 * 2);
  float* ml   = (float*)(ws + ((size_t)48 << 20) + ((size_t)1 << 19)); // [4][16384][2] f32
  bf16* Opart = (bf16*)(ws + ((size_t)49 << 20));          // [4][16384][256] bf16, 49..81 MB

  wconv_kernel<<<dim3(256), dim3(256), 0, stream>>>(qw, pw, wqb, wpb);
  gn_kernel<<<dim3(128), dim3(256), 0, stream>>>(x, gnw, gnb, ht);
  qkv_gemm<<<dim3(768), dim3(256), 0, stream>>>(ht, wqb, qb, qkvt);
  kprep_kernel<<<dim3(512), dim3(256), 0, stream>>>(qkvt, Kf);
  vfrag_kernel<<<dim3(1024), dim3(256), 0, stream>>>(qkvt, Vf);
  attn_kernel<<<dim3(1024), dim3(256), 0, stream>>>(qkvt, Kf, Vf, Opart, ml);
  combine_kernel<<<dim3(512), dim3(256), 0, stream>>>(Opart, ml, ho);
  proj_gemm<<<dim3(256), dim3(256), 0, stream>>>(ho, wpb, pb, x, out);
}

// Round 8
// 214.049 us; speedup vs baseline: 7.8051x; 7.8051x over previous
//
#include <hip/hip_runtime.h>
#include <hip/hip_bf16.h>

#define DEVI __device__ __forceinline__

typedef short bf16x8 __attribute__((ext_vector_type(8)));
typedef float f32x4  __attribute__((ext_vector_type(4)));
typedef float f32x16 __attribute__((ext_vector_type(16)));
typedef unsigned short u16;
typedef unsigned int u32;

using bf16 = __hip_bfloat16;

DEVI bf16x8 ld8(const bf16* p) { return *reinterpret_cast<const bf16x8*>(p); }

DEVI u16 f2bu(float f) {
  union { bf16 h; u16 u; } c; c.h = __float2bfloat16(f); return c.u;
}
DEVI float b2f(u16 u) {
  union { float f; unsigned int i; } c; c.i = ((unsigned int)u) << 16; return c.f;
}

DEVI void gload_lds16(const void* g, void* l) {
  typedef const __attribute__((address_space(1))) char* gp_t;
  typedef __attribute__((address_space(3))) char* lp_t;
  __builtin_amdgcn_global_load_lds((gp_t)g, (lp_t)l, 16, 0, 0);
}

DEVI u32 pk_fp8(float a, float b, float c, float d) {
  int t = __builtin_amdgcn_cvt_pk_fp8_f32(a, b, 0, false);
  t = __builtin_amdgcn_cvt_pk_fp8_f32(c, d, t, true);
  return (u32)t;
}

#define MFMA16(a, b, c) __builtin_amdgcn_mfma_f32_16x16x32_bf16((a), (b), (c), 0, 0, 0)
#define MFMA32(a, b, c) __builtin_amdgcn_mfma_f32_32x32x16_bf16((a), (b), (c), 0, 0, 0)
#define MFMA32F8(a, b, c) __builtin_amdgcn_mfma_f32_32x32x16_fp8_fp8((a), (b), (c), 0, 0, 0)

// Sizes: B=4, C=256, N=4096 (64x64), 3C=768, groups=32 (8 ch each)

// ---------------- K0: weights fp32 -> bf16 ----------------
__global__ __launch_bounds__(256) void wconv_kernel(const float* __restrict__ wq,
                                                    const float* __restrict__ wp,
                                                    bf16* __restrict__ wqb,
                                                    bf16* __restrict__ wpb) {
  int tid = blockIdx.x * 256 + threadIdx.x;
  const bool isq = tid < 49152;
  float4 v = isq ? ((const float4*)wq)[tid] : ((const float4*)wp)[tid - 49152];
  alignas(8) bf16 o[4] = { __float2bfloat16(v.x), __float2bfloat16(v.y),
                           __float2bfloat16(v.z), __float2bfloat16(v.w) };
  uint2 pk = *reinterpret_cast<uint2*>(o);
  if (isq) ((uint2*)wqb)[tid] = pk;
  else     ((uint2*)wpb)[tid - 49152] = pk;
}

// ---------------- K1: GroupNorm -> ht[b][n][c] bf16 ----------------
__global__ __launch_bounds__(256) void gn_kernel(const float* __restrict__ x,
                                                 const float* __restrict__ gw,
                                                 const float* __restrict__ gb,
                                                 bf16* __restrict__ ht) {
  const int blk = blockIdx.x;            // b*32 + g
  const int bb = blk >> 5, g = blk & 31;
  const float* xg = x + (size_t)(bb * 256 + g * 8) * 4096;

  float s = 0.f, ss = 0.f;
  const float4* x4 = (const float4*)xg;
  for (int i = threadIdx.x; i < 8192; i += 256) {
    float4 v = x4[i];
    s  += v.x + v.y + v.z + v.w;
    ss += v.x * v.x + v.y * v.y + v.z * v.z + v.w * v.w;
  }
  #pragma unroll
  for (int off = 32; off; off >>= 1) {
    s  += __shfl_down(s, off);
    ss += __shfl_down(ss, off);
  }
  __shared__ float red[8];
  int wave = threadIdx.x >> 6;
  if ((threadIdx.x & 63) == 0) { red[wave * 2] = s; red[wave * 2 + 1] = ss; }
  __syncthreads();
  if (threadIdx.x == 0) {
    float S = red[0] + red[2] + red[4] + red[6];
    float SS = red[1] + red[3] + red[5] + red[7];
    float mu = S * (1.f / 32768.f);
    float var = SS * (1.f / 32768.f) - mu * mu;
    red[0] = mu; red[1] = rsqrtf(var + 1e-5f);
  }
  __syncthreads();
  const float mu = red[0], rstd = red[1];

  float gm[8], bt[8];
  #pragma unroll
  for (int j = 0; j < 8; ++j) {
    float wv = gw[g * 8 + j] * rstd;
    gm[j] = wv; bt[j] = gb[g * 8 + j] - mu * wv;
  }
  bf16* hrow = ht + (size_t)bb * 4096 * 256 + g * 8;
  for (int n = threadIdx.x; n < 4096; n += 256) {
    alignas(16) u16 u[8];
    #pragma unroll
    for (int j = 0; j < 8; ++j)
      u[j] = f2bu(xg[j * 4096 + n] * gm[j] + bt[j]);
    *reinterpret_cast<uint4*>(hrow + (size_t)n * 256) = *reinterpret_cast<uint4*>(u);
  }
}

// ---------------- K2: QKV GEMM (staged), qkvt[n][o] = ht[n][c]*W[o][c]^T + bias ----------------
__global__ __launch_bounds__(256, 2) void qkv_gemm(const bf16* __restrict__ ht,
                                                   const bf16* __restrict__ wq,
                                                   const float* __restrict__ qkvb,
                                                   bf16* __restrict__ qkvt) {
  const int phys = blockIdx.x;
  const int L = (phys & 7) * 96 + (phys >> 3);
  const int bb = L / 192; const int rem = L - bb * 192;
  const int nt = rem / 6, ot = rem - nt * 6;

  const int tid = threadIdx.x, lane = tid & 63, w = tid >> 6;
  const int ln = lane & 15, hi = lane >> 4;
  const int wr = w >> 1, wc = w & 1;
  const int n_base = nt * 128, o_base = ot * 128;
  const bf16* hb = ht + (size_t)bb * 4096 * 256;

  __shared__ bf16 At[2][128 * 64];   // row-major [128][64ch], slot swz: g ^= (row&7)
  __shared__ bf16 Bt[2][128 * 64];

  f32x4 acc[4][4] = {};

  {
    #pragma unroll
    for (int i = 0; i < 4; ++i) {
      int G = i * 256 + tid; int row = G >> 3, g = G & 7;
      int cofs = (g ^ (row & 7)) << 3;
      gload_lds16(hb + (size_t)(n_base + row) * 256 + cofs, At[0] + (size_t)G * 8);
      gload_lds16(wq + (size_t)(o_base + row) * 256 + cofs, Bt[0] + (size_t)G * 8);
    }
  }
  __syncthreads();

  int cur = 0;
  for (int ks = 0; ks < 4; ++ks) {
    if (ks < 3) {
      int k0 = (ks + 1) * 64;
      #pragma unroll
      for (int i = 0; i < 4; ++i) {
        int G = i * 256 + tid; int row = G >> 3, g = G & 7;
        int cofs = k0 + ((g ^ (row & 7)) << 3);
        gload_lds16(hb + (size_t)(n_base + row) * 256 + cofs, At[cur ^ 1] + (size_t)G * 8);
        gload_lds16(wq + (size_t)(o_base + row) * 256 + cofs, Bt[cur ^ 1] + (size_t)G * 8);
      }
    }
    const char* Ab = (const char*)At[cur];
    const char* Bb = (const char*)Bt[cur];
    __builtin_amdgcn_s_setprio(1);
    #pragma unroll
    for (int cb = 0; cb < 2; ++cb) {
      bf16x8 af[4], bfr[4];
      #pragma unroll
      for (int i = 0; i < 4; ++i) {
        int row = wr * 64 + i * 16 + ln;
        af[i] = *(const bf16x8*)(Ab + row * 128 + (((cb * 4 + hi) ^ (row & 7)) << 4));
      }
      #pragma unroll
      for (int j = 0; j < 4; ++j) {
        int row = wc * 64 + j * 16 + ln;
        bfr[j] = *(const bf16x8*)(Bb + row * 128 + (((cb * 4 + hi) ^ (row & 7)) << 4));
      }
      #pragma unroll
      for (int i = 0; i < 4; ++i)
        #pragma unroll
        for (int j = 0; j < 4; ++j)
          acc[i][j] = MFMA16(af[i], bfr[j], acc[i][j]);
    }
    __builtin_amdgcn_s_setprio(0);
    __syncthreads();
    cur ^= 1;
  }

  const float sc = (ot < 2) ? 0.0625f : 1.0f;   // fold 1/sqrt(C)=1/16 into Q
  bf16* ob = qkvt + (size_t)bb * 4096 * 768;
  #pragma unroll
  for (int j = 0; j < 4; ++j) {
    int o = o_base + wc * 64 + j * 16 + ln;
    float bias = qkvb[o];
    #pragma unroll
    for (int i = 0; i < 4; ++i)
      #pragma unroll
      for (int r = 0; r < 4; ++r) {
        int n = n_base + wr * 64 + i * 16 + hi * 4 + r;
        ob[(size_t)n * 768 + o] = __float2bfloat16((acc[i][j][r] + bias) * sc);
      }
  }
}

// ---------------- K3: V -> fragment-major fp8: vf[bb][kvb][s][c][8] ----------------
// vf granule (kvb, s, c) byte j = fp8(V[kvb*32 + s*8 + j][c]); 8KB per kvb.
__global__ __launch_bounds__(256) void vfp8_kernel(const bf16* __restrict__ qkvt,
                                                   unsigned char* __restrict__ vf) {
  int bid = blockIdx.x;
  int ct = bid & 3, ntile = (bid >> 2) & 63, bb = bid >> 8;
  __shared__ bf16 T[64][72];
  int tid = threadIdx.x;
  int i = tid >> 3, j8 = (tid & 7) * 8;
  const bf16* src = qkvt + (size_t)bb * 4096 * 768 + (size_t)(ntile * 64 + i) * 768 + 512 + ct * 64 + j8;
  #pragma unroll
  for (int p = 0; p < 2; ++p) {
    bf16x8 v = ld8(src + (size_t)p * 32 * 768);
    *reinterpret_cast<bf16x8*>(&T[i + p * 32][j8]) = v;   // T[n-local][c-local]
  }
  __syncthreads();
  #pragma unroll
  for (int p = 0; p < 2; ++p) {
    int u = p * 256 + tid;                    // 0..511
    int cl = u & 63, s = (u >> 6) & 3, k2 = u >> 8;
    float e[8];
    #pragma unroll
    for (int j = 0; j < 8; ++j)
      e[j] = __bfloat162float(T[k2 * 32 + s * 8 + j][cl]);
    uint2 pk;
    pk.x = pk_fp8(e[0], e[1], e[2], e[3]);
    pk.y = pk_fp8(e[4], e[5], e[6], e[7]);
    size_t off = (((size_t)(bb * 128 + ntile * 2 + k2) * 4 + s) * 256 + (ct * 64 + cl)) * 8;
    *reinterpret_cast<uint2*>(vf + off) = pk;
  }
}

// ---------------- K4: flash attention, 32x32 MFMA, swapped QK^T, fp8 PV ----------------
// grid 512, 256 threads (4 waves x 32 q-rows), 2+ blocks/CU (LDS 48KB).
// K[32][256] bf16 dbuf (32KB) + V fp8 frag-major dbuf (16KB).
__global__ __launch_bounds__(256, 2) void attn_kernel(const bf16* __restrict__ qkvt,
                                                      const unsigned char* __restrict__ vf,
                                                      bf16* __restrict__ Opart,
                                                      float* __restrict__ ml) {
  const int phys = blockIdx.x;
  const int x = phys & 7, c = phys >> 3;          // XCD, chunk-local (0..63)
  const int gs = x * 2 + (c >> 5);                // global slice = bb*4+sp (0..15)
  const int qt = c & 31;
  const int bb = gs >> 2, sp = gs & 3;

  const int tid = threadIdx.x, lane = tid & 63, w = tid >> 6;
  const int ln32 = lane & 31, h = lane >> 5;
  const bool h0 = (h == 0);
  const int n0w = qt * 128 + w * 32;

  const bf16* qb = qkvt + (size_t)bb * 4096 * 768;
  const unsigned char* vb = vf + (size_t)bb * 1048576;

  __shared__ bf16 KT[2][32 * 256];          // 2 x 16KB, granule swz: g ^= row
  __shared__ unsigned char VT2[2][8192];    // 2 x 8KB fp8, [s(4)][c(256)][8B], linear

  // Q fragments (B-operand of S^T mfma): 32 q-rows x 256 ch (pre-scaled 1/16)
  bf16x8 aq[16];
  #pragma unroll
  for (int step = 0; step < 16; ++step)
    aq[step] = ld8(qb + (size_t)(n0w + ln32) * 768 + step * 16 + h * 8);

  f32x16 acc[8] = {};
  float m_run = -3.0e38f, lsum = 0.f;

  // ---- prologue: stage tile 0 ----
  {
    int m0 = sp * 1024;
    const unsigned char* vsrc = vb + (size_t)(sp * 32) * 8192;
    #pragma unroll
    for (int i = 0; i < 4; ++i) {
      int G = i * 256 + tid;
      int kr = G >> 5, kc = G & 31;
      gload_lds16(qb + (size_t)(m0 + kr) * 768 + 256 + ((kc ^ kr) << 3), KT[0] + (size_t)G * 8);
    }
    #pragma unroll
    for (int i = 0; i < 2; ++i) {
      int G = i * 256 + tid;
      gload_lds16(vsrc + (size_t)G * 16, VT2[0] + (size_t)G * 16);
    }
  }
  __syncthreads();

  int cur = 0;
  for (int t = 0; t < 32; ++t) {
    // ---- issue stage of next tile (overlaps with this tile's compute) ----
    if (t < 31) {
      int kvbn = sp * 32 + t + 1;
      int m0n = kvbn * 32;
      const unsigned char* vsrc = vb + (size_t)kvbn * 8192;
      #pragma unroll
      for (int i = 0; i < 4; ++i) {
        int G = i * 256 + tid;
        int kr = G >> 5, kc = G & 31;
        gload_lds16(qb + (size_t)(m0n + kr) * 768 + 256 + ((kc ^ kr) << 3), KT[cur ^ 1] + (size_t)G * 8);
      }
      #pragma unroll
      for (int i = 0; i < 2; ++i) {
        int G = i * 256 + tid;
        gload_lds16(vsrc + (size_t)G * 16, VT2[cur ^ 1] + (size_t)G * 16);
      }
    }

    const char* Kb = (const char*)KT[cur];
    const char* Vb = (const char*)VT2[cur];

    // ---- S^T = K . Q^T : lane holds P-row q=ln32, kv = (r&3)+8*(r>>2)+4h ----
    f32x16 s0 = {};
    __builtin_amdgcn_s_setprio(1);
    #pragma unroll
    for (int step = 0; step < 16; ++step) {
      bf16x8 k0 = *(const bf16x8*)(Kb + ln32 * 512 + (((step * 2 + h) ^ ln32) << 4));
      s0 = MFMA32(k0, aq[step], s0);
    }
    __builtin_amdgcn_s_setprio(0);

    // ---- row max (q=ln32 lives at lanes {ln32, ln32+32}) ----
    float mx = -3.0e38f;
    #pragma unroll
    for (int r = 0; r < 16; ++r) mx = fmaxf(mx, s0[r]);
    mx = fmaxf(mx, __shfl_xor(mx, 32));

    // ---- defer-max rescale (THR=6 so P <= e^6 = 403 < fp8 max 448) ----
    if (__any(mx > m_run + 6.f)) {
      float mnew = fmaxf(m_run, mx);
      float alpha = __expf(m_run - mnew);
      m_run = mnew;
      lsum *= alpha;
      #pragma unroll
      for (int r = 0; r < 16; ++r) {
        int qacc = (r & 3) + 8 * (r >> 2) + 4 * h;
        float ar = __shfl(alpha, qacc);
        #pragma unroll
        for (int ct = 0; ct < 8; ++ct) acc[ct][r] *= ar;
      }
    }

    // ---- P = exp(S - m) packed to fp8 (4 per u32, kv-ascending) ----
    u32 pq[4], swq[4];
    #pragma unroll
    for (int g = 0; g < 4; ++g) {
      float e0 = __expf(s0[4 * g]     - m_run);
      float e1 = __expf(s0[4 * g + 1] - m_run);
      float e2 = __expf(s0[4 * g + 2] - m_run);
      float e3 = __expf(s0[4 * g + 3] - m_run);
      lsum += (e0 + e1) + (e2 + e3);
      pq[g] = pk_fp8(e0, e1, e2, e3);
    }
    #pragma unroll
    for (int g = 0; g < 4; ++g) swq[g] = __shfl_xor(pq[g], 32);

    // ---- O += P V (fp8 x fp8 MFMA) ----
    __builtin_amdgcn_s_setprio(1);
    #pragma unroll
    for (int st = 0; st < 2; ++st) {
      union { u32 u[2]; long long l; } a_;
      a_.u[0] = h0 ? pq[2 * st]  : swq[2 * st + 1];
      a_.u[1] = h0 ? swq[2 * st] : pq[2 * st + 1];
      #pragma unroll
      for (int ct = 0; ct < 8; ++ct) {
        long long bvl = *(const long long*)(Vb + (st * 2 + h) * 2048 + (ct * 32 + ln32) * 8);
        acc[ct] = MFMA32F8(a_.l, bvl, acc[ct]);
      }
    }
    __builtin_amdgcn_s_setprio(0);

    __syncthreads();   // drains vmcnt: publishes next tile, protects cur tile
    cur ^= 1;
  }

  // ---- epilogue ----
  float Lrow = lsum + __shfl_xor(lsum, 32);
  size_t rb = (size_t)sp * 16384 + (size_t)bb * 4096;
  if (lane < 32) {
    ml[(rb + n0w + lane) * 2]     = m_run;
    ml[(rb + n0w + lane) * 2 + 1] = Lrow;
  }
  bf16* ob = Opart + rb * 256;
  #pragma unroll
  for (int r = 0; r < 16; ++r) {
    int qacc = (r & 3) + 8 * (r >> 2) + 4 * h;
    int n = n0w + qacc;
    #pragma unroll
    for (int ct = 0; ct < 8; ++ct)
      ob[(size_t)n * 256 + ct * 32 + ln32] = __float2bfloat16(acc[ct][r]);
  }
}

// ---------------- K4b: combine split-KV partials -> ho[b][n][c] ----------------
__global__ __launch_bounds__(256) void combine_kernel(const bf16* __restrict__ Opart,
                                                      const float* __restrict__ ml,
                                                      bf16* __restrict__ ho) {
  int rowg = blockIdx.x * 32 + (threadIdx.x >> 3);   // b*4096 + n
  int cg = (threadIdx.x & 7) * 32;
  float msp[4]; float M = -3.0e38f;
  #pragma unroll
  for (int sp = 0; sp < 4; ++sp) {
    msp[sp] = ml[((size_t)sp * 16384 + rowg) * 2];
    M = fmaxf(M, msp[sp]);
  }
  float acc[32];
  #pragma unroll
  for (int j = 0; j < 32; ++j) acc[j] = 0.f;
  float Ltot = 0.f;
  #pragma unroll
  for (int sp = 0; sp < 4; ++sp) {
    float sc = __expf(msp[sp] - M);
    Ltot += ml[((size_t)sp * 16384 + rowg) * 2 + 1] * sc;
    const bf16* p = Opart + ((size_t)sp * 16384 + rowg) * 256 + cg;
    #pragma unroll
    for (int v = 0; v < 4; ++v) {
      bf16x8 u = ld8(p + v * 8);
      #pragma unroll
      for (int j = 0; j < 8; ++j) acc[v * 8 + j] += sc * b2f((u16)u[j]);
    }
  }
  float inv = 1.f / Ltot;
  bf16* o = ho + (size_t)rowg * 256 + cg;
  #pragma unroll
  for (int v = 0; v < 4; ++v) {
    alignas(16) u16 u[8];
    #pragma unroll
    for (int j = 0; j < 8; ++j) u[j] = f2bu(acc[v * 8 + j] * inv);
    *reinterpret_cast<uint4*>(o + v * 8) = *reinterpret_cast<uint4*>(u);
  }
}

// ---------------- K5: proj GEMM (staged) + residual ----------------
__global__ __launch_bounds__(256, 2) void proj_gemm(const bf16* __restrict__ ho,
                                                    const bf16* __restrict__ wp,
                                                    const float* __restrict__ pb,
                                                    const float* __restrict__ x,
                                                    float* __restrict__ out) {
  const int phys = blockIdx.x;
  const int L = (phys & 7) * 32 + (phys >> 3);
  const int bb = L >> 6; const int rem = L & 63;
  const int ot = rem >> 5, nt = rem & 31;

  const int tid = threadIdx.x, lane = tid & 63, w = tid >> 6;
  const int ln = lane & 15, hi = lane >> 4;
  const int wr = w >> 1, wc = w & 1;
  const int o_base = ot * 128, n_base = nt * 128;
  const bf16* hb = ho + (size_t)bb * 4096 * 256;

  __shared__ bf16 Wt[2][128 * 64];
  __shared__ bf16 Ht[2][128 * 64];

  f32x4 acc[4][4] = {};

  {
    #pragma unroll
    for (int i = 0; i < 4; ++i) {
      int G = i * 256 + tid; int row = G >> 3, g = G & 7;
      int cofs = (g ^ (row & 7)) << 3;
      gload_lds16(wp + (size_t)(o_base + row) * 256 + cofs, Wt[0] + (size_t)G * 8);
      gload_lds16(hb + (size_t)(n_base + row) * 256 + cofs, Ht[0] + (size_t)G * 8);
    }
  }
  __syncthreads();

  int cur = 0;
  for (int ks = 0; ks < 4; ++ks) {
    if (ks < 3) {
      int k0 = (ks + 1) * 64;
      #pragma unroll
      for (int i = 0; i < 4; ++i) {
        int G = i * 256 + tid; int row = G >> 3, g = G & 7;
        int cofs = k0 + ((g ^ (row & 7)) << 3);
        gload_lds16(wp + (size_t)(o_base + row) * 256 + cofs, Wt[cur ^ 1] + (size_t)G * 8);
        gload_lds16(hb + (size_t)(n_base + row) * 256 + cofs, Ht[cur ^ 1] + (size_t)G * 8);
      }
    }
    const char* Ab = (const char*)Wt[cur];
    const char* Bb = (const char*)Ht[cur];
    __builtin_amdgcn_s_setprio(1);
    #pragma unroll
    for (int cb = 0; cb < 2; ++cb) {
      bf16x8 af[4], bfr[4];
      #pragma unroll
      for (int i = 0; i < 4; ++i) {
        int row = wr * 64 + i * 16 + ln;
        af[i] = *(const bf16x8*)(Ab + row * 128 + (((cb * 4 + hi) ^ (row & 7)) << 4));
      }
      #pragma unroll
      for (int j = 0; j < 4; ++j) {
        int row = wc * 64 + j * 16 + ln;
        bfr[j] = *(const bf16x8*)(Bb + row * 128 + (((cb * 4 + hi) ^ (row & 7)) << 4));
      }
      #pragma unroll
      for (int i = 0; i < 4; ++i)
        #pragma unroll
        for (int j = 0; j < 4; ++j)
          acc[i][j] = MFMA16(af[i], bfr[j], acc[i][j]);
    }
    __builtin_amdgcn_s_setprio(0);
    __syncthreads();
    cur ^= 1;
  }

  const float* xb = x + (size_t)bb * 256 * 4096;
  float* ob = out + (size_t)bb * 256 * 4096;
  #pragma unroll
  for (int i = 0; i < 4; ++i)
    #pragma unroll
    for (int r = 0; r < 4; ++r) {
      int o = o_base + wr * 64 + i * 16 + hi * 4 + r;
      float bias = pb[o];
      #pragma unroll
      for (int j = 0; j < 4; ++j) {
        int n = n_base + wc * 64 + j * 16 + ln;
        size_t idx = (size_t)o * 4096 + n;
        ob[idx] = xb[idx] + bias + acc[i][j][r];
      }
    }
}

extern "C" void kernel_launch(void* const* d_in, const int* in_sizes, int n_in,
                              void* d_out, int out_size, void* d_ws, size_t ws_size,
                              hipStream_t stream) {
  const float* x   = (const float*)d_in[0];
  const float* gnw = (const float*)d_in[1];
  const float* gnb = (const float*)d_in[2];
  const float* qw  = (const float*)d_in[3];
  const float* qb  = (const float*)d_in[4];
  const float* pw  = (const float*)d_in[5];
  const float* pb  = (const float*)d_in[6];
  float* out = (float*)d_out;

  char* ws = (char*)d_ws;
  bf16* ht    = (bf16*)(ws);                               // [4][4096][256]  0..8 MB
  bf16* qkvt  = (bf16*)(ws + ((size_t)8 << 20));           // [4][4096][768]  8..32 MB
  unsigned char* vf = (unsigned char*)(ws + ((size_t)32 << 20)); // fp8 V_frag [4][1M] 32..36 MB
  bf16* ho    = (bf16*)(ws + ((size_t)40 << 20));          // [4][4096][256]  40..48 MB
  bf16* wqb   = (bf16*)(ws + ((size_t)48 << 20));          // [768][256]
  bf16* wpb   = (bf16*)(ws + ((size_t)48 << 20) + 768 * 256 * 2);
  float* ml   = (float*)(ws + ((size_t)48 << 20) + ((size_t)1 << 19)); // [4][16384][2] f32
  bf16* Opart = (bf16*)(ws + ((size_t)49 << 20));          // [4][16384][256] bf16, 49..81 MB

  wconv_kernel<<<dim3(256), dim3(256), 0, stream>>>(qw, pw, wqb, wpb);
  gn_kernel<<<dim3(128), dim3(256), 0, stream>>>(x, gnw, gnb, ht);
  qkv_gemm<<<dim3(768), dim3(256), 0, stream>>>(ht, wqb, qb, qkvt);
  vfp8_kernel<<<dim3(1024), dim3(256), 0, stream>>>(qkvt, vf);
  attn_kernel<<<dim3(512), dim3(256), 0, stream>>>(qkvt, vf, Opart, ml);
  combine_kernel<<<dim3(512), dim3(256), 0, stream>>>(Opart, ml, ho);
  proj_gemm<<<dim3(256), dim3(256), 0, stream>>>(ho, wpb, pb, x, out);
}